// Round 7
// baseline (645.488 us; speedup 1.0000x reference)
//
#include <hip/hip_runtime.h>

typedef __bf16 bf16;
typedef __bf16 bf16x8 __attribute__((ext_vector_type(8)));
typedef float  f32x4  __attribute__((ext_vector_type(4)));

#define MFMA16(a, b, c) __builtin_amdgcn_mfma_f32_16x16x32_bf16((a), (b), (c), 0, 0, 0)

// async global->LDS, 16B per lane; LDS dest = wave-uniform base + lane*16
#define GLOAD_LDS16(gptr, lptr)                                              \
    __builtin_amdgcn_global_load_lds(                                        \
        (const __attribute__((address_space(1))) unsigned int*)(gptr),       \
        (__attribute__((address_space(3))) unsigned int*)(lptr), 16, 0, 0)

constexpr int kDM = 1024;
constexpr int kNTOK = 32768;   // V token count (vt row stride)

static __device__ inline f32x4 zero4() { f32x4 z = {0.f, 0.f, 0.f, 0.f}; return z; }

// ---------------------------------------------------------------------------
// Streaming fp32 -> bf16 convert of q, k, v in ONE launch (RNE rounding).
// dst: Xq [2048*1024] | Xk [32768*1024] | Xv [32768*1024] bf16, contiguous.
// ---------------------------------------------------------------------------
__global__ __launch_bounds__(256) void cvt_all(
    const float* __restrict__ q, const float* __restrict__ k,
    const float* __restrict__ v, bf16* __restrict__ dst)
{
    const int q8 = 262144, k8 = 4194304;          // 8-elem group counts
    const int tot = q8 + 2 * k8;
    int idx = blockIdx.x * 256 + threadIdx.x;
    const int stride = gridDim.x * 256;
    for (; idx < tot; idx += stride) {
        const float* s;
        if (idx < q8)            s = q + (size_t)idx * 8;
        else if (idx < q8 + k8)  s = k + (size_t)(idx - q8) * 8;
        else                     s = v + (size_t)(idx - q8 - k8) * 8;
        const float4 u0 = *(const float4*)s;
        const float4 u1 = *(const float4*)(s + 4);
        bf16x8 w;
        w[0] = (bf16)u0.x; w[1] = (bf16)u0.y; w[2] = (bf16)u0.z; w[3] = (bf16)u0.w;
        w[4] = (bf16)u1.x; w[5] = (bf16)u1.y; w[6] = (bf16)u1.z; w[7] = (bf16)u1.w;
        *(bf16x8*)&dst[(size_t)idx * 8] = w;
    }
}

// ---------------------------------------------------------------------------
// All three W fp32 [k][n] -> Wt bf16 [n][k] transposes in one launch.
// ---------------------------------------------------------------------------
__global__ __launch_bounds__(256) void transpose_all(
    const float* __restrict__ Wq, const float* __restrict__ Wk,
    const float* __restrict__ Wv, bf16* __restrict__ Wqt,
    bf16* __restrict__ Wkt, bf16* __restrict__ Wvt)
{
    __shared__ bf16 T[64][68];
    const float* W = (blockIdx.z == 0) ? Wq : (blockIdx.z == 1) ? Wk : Wv;
    bf16* Wt       = (blockIdx.z == 0) ? Wqt : (blockIdx.z == 1) ? Wkt : Wvt;
    const int tid = threadIdx.x;
    const int n0 = blockIdx.x * 64, k0 = blockIdx.y * 64;
    #pragma unroll
    for (int i = 0; i < 4; i++) {
        const int kk = (tid >> 4) + i * 16, nn4 = (tid & 15) * 4;
        float4 v = *(const float4*)&W[(size_t)(k0 + kk) * kDM + n0 + nn4];
        T[nn4 + 0][kk] = (bf16)v.x; T[nn4 + 1][kk] = (bf16)v.y;
        T[nn4 + 2][kk] = (bf16)v.z; T[nn4 + 3][kk] = (bf16)v.w;
    }
    __syncthreads();
    #pragma unroll
    for (int i = 0; i < 4; i++) {
        const int nn = (tid >> 4) + i * 16, kc = (tid & 15) * 4;
        *(ushort4*)&Wt[(size_t)(n0 + nn) * kDM + k0 + kc] = *(const ushort4*)&T[nn][kc];
    }
}

// ---------------------------------------------------------------------------
// Merged QKV GEMM + fused epilogues (round-4-verified 128x128 inner loop).
// Blocks [0,2048): K-proj (mode2, fast RoPE).  [2048,4096): V-proj (mode3,
// V^T store).  [4096,4224): Q-proj (mode1, slow RoPE).
// 128x128 tile, BK=64, 4 waves 2x2.  Double-buffered staging (2x32KB LDS),
// both operands via global_load_lds w=16 (linear dest, XOR-pre-swizzled
// source).  Per K-step: issue next tile's 8 loads FIRST, compute current
// tile, then ONE vmcnt(0)+s_barrier.
// ---------------------------------------------------------------------------
__global__ __launch_bounds__(256) void gemm_all(
    const bf16* __restrict__ Xq, const bf16* __restrict__ Xk,
    const bf16* __restrict__ Xv, const bf16* __restrict__ Wqt,
    const bf16* __restrict__ Wkt, const bf16* __restrict__ Wvt,
    const float* __restrict__ bq, const float* __restrict__ bk,
    const float* __restrict__ bv, bf16* __restrict__ qh,
    bf16* __restrict__ kh, bf16* __restrict__ vt)
{
    __shared__ char smem[65536];         // 2 x {A [128][64], B [128][64]} bf16
    bf16* Y = (bf16*)smem;               // epilogue buffer [128][136] (34.8KB)

    int b = blockIdx.x;
    const bf16* X; const bf16* Wt; const float* bias; bf16* out;
    int mtiles, mode;
    if (b < 2048)      { X = Xk; Wt = Wkt; bias = bk; out = kh; mtiles = 32; mode = 2; }
    else if (b < 4096) { b -= 2048; X = Xv; Wt = Wvt; bias = bv; out = vt; mtiles = 32; mode = 3; }
    else               { b -= 4096; X = Xq; Wt = Wqt; bias = bq; out = qh; mtiles = 2;  mode = 1; }

    const int xcd  = b & 7;
    const int s    = b >> 3;
    const int m0   = (xcd * mtiles + (s >> 3)) * 128;
    const int n0   = (s & 7) * 128;
    const int tid  = threadIdx.x;
    const int wave = tid >> 6;
    const int lane = tid & 63;
    const int quad = lane >> 4, l16 = lane & 15;
    const int mb   = (wave & 1) * 64, nb = (wave >> 1) * 64;
    const int r8   = lane >> 3, j8 = lane & 7;   // staging coords

    f32x4 acc[4][4];
    #pragma unroll
    for (int i = 0; i < 4; i++)
        #pragma unroll
        for (int j = 0; j < 4; j++) acc[i][j] = zero4();

    // stage one 64-K slab of A and B into buffer `buf` (8 gload_lds/thread)
    auto stage = [&](int k0, char* buf) {
        bf16* Ab = (bf16*)buf;
        bf16* Bb = (bf16*)(buf + 16384);
        #pragma unroll
        for (int i = 0; i < 4; i++) {
            const int c = wave * 4 + i;
            const int row = c * 8 + r8;
            const int off = (j8 ^ (row & 7)) * 8;
            GLOAD_LDS16(&X[(size_t)(m0 + row) * kDM + k0 + off],  &Ab[c * 512]);
            GLOAD_LDS16(&Wt[(size_t)(n0 + row) * kDM + k0 + off], &Bb[c * 512]);
        }
    };

    // prologue: stage tile 0
    stage(0, smem);
    asm volatile("s_waitcnt vmcnt(0)" ::: "memory");
    __builtin_amdgcn_s_barrier();

    for (int t = 0; t < 16; ++t) {
        const char* cur = smem + (t & 1) * 32768;
        if (t < 15) stage((t + 1) * 64, smem + ((t + 1) & 1) * 32768);
        __builtin_amdgcn_sched_barrier(0);   // pin prefetch issue above compute

        const bf16* Ab = (const bf16*)cur;
        const bf16* Bb = (const bf16*)(cur + 16384);
        #pragma unroll
        for (int ks = 0; ks < 2; ks++) {
            const int G = ks * 4 + quad;
            bf16x8 a[4], bfr[4];
            #pragma unroll
            for (int i = 0; i < 4; i++)
                a[i] = *(const bf16x8*)&Ab[(mb + i * 16 + l16) * 64 + ((G ^ (l16 & 7)) * 8)];
            #pragma unroll
            for (int j = 0; j < 4; j++)
                bfr[j] = *(const bf16x8*)&Bb[(nb + j * 16 + l16) * 64 + ((G ^ (l16 & 7)) * 8)];
            #pragma unroll
            for (int i = 0; i < 4; i++)
                #pragma unroll
                for (int j = 0; j < 4; j++)
                    acc[i][j] = MFMA16(a[i], bfr[j], acc[i][j]);
        }

        if (t < 15) asm volatile("s_waitcnt vmcnt(0)" ::: "memory");  // next tile landed
        __builtin_amdgcn_sched_barrier(0);
        __builtin_amdgcn_s_barrier();        // everyone done reading cur
    }

    __syncthreads();   // staging region about to be reused as Y

    if (mode == 3) {
        // transposed epilogue: Y[n][m], then vectorized store to out[n][token]
        #pragma unroll
        for (int j = 0; j < 4; j++) {
            const int n = nb + j * 16 + l16;
            const float bv2 = bias[n0 + n];
            #pragma unroll
            for (int i = 0; i < 4; i++) {
                const int m = mb + i * 16 + quad * 4;
                bf16 tmp[4];
                #pragma unroll
                for (int r = 0; r < 4; r++) tmp[r] = (bf16)(acc[i][j][r] + bv2);
                *(ushort4*)&Y[n * 136 + m] = *(const ushort4*)tmp;
            }
        }
        __syncthreads();
        const int row = tid >> 1, seg = (tid & 1) * 64;
        #pragma unroll
        for (int kk = 0; kk < 8; kk++)
            *(uint4*)&out[(size_t)(n0 + row) * kNTOK + m0 + seg + kk * 8] =
                *(const uint4*)&Y[row * 136 + seg + kk * 8];
    } else {
        // RoPE epilogue. phase 1: waves 2,3 deposit x2 (d in [64,128)).
        if (wave >= 2) {
            #pragma unroll
            for (int j = 0; j < 4; j++) {
                const int dcol = 64 + j * 16 + l16;
                const float bv2 = bias[n0 + dcol];
                #pragma unroll
                for (int i = 0; i < 4; i++)
                    #pragma unroll
                    for (int r = 0; r < 4; r++)
                        Y[(mb + i * 16 + quad * 4 + r) * 136 + dcol] =
                            (bf16)(acc[i][j][r] + bv2);
            }
        }
        __syncthreads();
        // phase 2: waves 0,1 rotate (they hold x1, d in [0,64))
        if (wave < 2) {
            #pragma unroll
            for (int j = 0; j < 4; j++) {
                const int d = j * 16 + l16;
                const float bv2 = bias[n0 + d];
                const float invf = exp2f((float)d * -0.20762050593045951f); // log2(1e4)/64
                #pragma unroll
                for (int i = 0; i < 4; i++) {
                    #pragma unroll
                    for (int r = 0; r < 4; r++) {
                        const int mloc = mb + i * 16 + quad * 4 + r;
                        const int tok = m0 + mloc;
                        int pt, ph, pw;
                        if (mode == 2) { pt = tok >> 10; ph = (tok >> 5) & 31; pw = tok & 31; }
                        else { int tq = tok >> 8; pt = (31 * tq) / 7;
                               ph = 2 * ((tok >> 4) & 15) + 1; pw = 2 * (tok & 15) + 1; }
                        const int p = (d < 16) ? pt : ((d < 40) ? ph : pw);
                        float sn, cs;
                        __sincosf((float)p * invf, &sn, &cs);
                        const float x1 = acc[i][j][r] + bv2;
                        const float x2 = (float)Y[mloc * 136 + 64 + d];
                        Y[mloc * 136 + d]      = (bf16)(x1 * cs - x2 * sn);
                        Y[mloc * 136 + 64 + d] = (bf16)(x2 * cs + x1 * sn);
                    }
                }
            }
        }
        __syncthreads();
        const int row = tid >> 1, seg = (tid & 1) * 64;
        #pragma unroll
        for (int kk = 0; kk < 8; kk++)
            *(uint4*)&out[(size_t)(m0 + row) * kDM + n0 + seg + kk * 8] =
                *(const uint4*)&Y[row * 136 + seg + kk * 8];
    }
}

// ---------------------------------------------------------------------------
// Flash attention, 4-way key split.  Flat 1024-block grid with XCD-aware
// sibling placement: the 4 qb-blocks sharing one (t,sp,h) K/V slice (512KB)
// are 8 apart in flat id -> consecutive on the SAME XCD -> the slice is
// L2-resident for the 3 re-readers.  (Round-6 verified: ~-10us total.)
// ---------------------------------------------------------------------------
__global__ __launch_bounds__(256) void attn_kernel(
    const bf16* __restrict__ qh, const bf16* __restrict__ kh,
    const bf16* __restrict__ vt, float* __restrict__ Opart, float* __restrict__ ml)
{
    __shared__ bf16 Ks[64 * 128];    // [key][d], 16B-granule swizzle by key&15
    __shared__ bf16 Vs[128 * 64];    // [d][key], 16B-granule swizzle by d&7
    __shared__ bf16 Ps[4][16][64];   // per-wave P, col ^ ((row&7)*8) swizzle

    const int tid  = threadIdx.x;
    const int b    = blockIdx.x;
    const int j    = b >> 3;
    const int g    = (b & 7) * 32 + (j >> 2);   // (z,h) group in [0,256)
    const int qb   = j & 3;
    const int h    = g & 7;
    const int z    = g >> 3;
    const int t    = z >> 2, sp = z & 3;
    const int wave = tid >> 6;
    const int lane = tid & 63;
    const int quad = lane >> 4, l16 = lane & 15;

    const int qrow = qb * 64 + wave * 16 + l16;
    const size_t qbase = ((size_t)(t * 256 + qrow)) * kDM + h * 128;
    bf16x8 aq[4];
    #pragma unroll
    for (int kb = 0; kb < 4; kb++)
        aq[kb] = *(const bf16x8*)&qh[qbase + kb * 32 + quad * 8];

    bf16x8 ones;
    #pragma unroll
    for (int e = 0; e < 8; e++) ones[e] = (bf16)1.0f;

    f32x4 o[9];
    #pragma unroll
    for (int j2 = 0; j2 < 9; j2++) o[j2] = zero4();
    float m_run[4];
    #pragma unroll
    for (int r = 0; r < 4; r++) m_run[r] = -1e30f;
    const float scale = 0.08838834764831845f;   // 1/sqrt(128)

    const int r16 = lane >> 4, j16 = lane & 15;  // K staging coords
    const int r8  = lane >> 3, j8  = lane & 7;   // V staging coords

    for (int kt = 0; kt < 16; kt++) {
        const int kbase = t * 4096 + sp * 1024 + kt * 64;
        __syncthreads();
        #pragma unroll
        for (int i = 0; i < 4; i++) {   // K: 16 chunks (4 key rows each)
            const int c = wave * 4 + i;
            const int krow = c * 4 + r16;
            GLOAD_LDS16(&kh[(size_t)(kbase + krow) * kDM + h * 128 + ((j16 ^ (krow & 15)) * 8)],
                        &Ks[c * 512]);
        }
        #pragma unroll
        for (int i = 0; i < 4; i++) {   // V^T: 16 chunks (8 d rows x 64 keys)
            const int c = wave * 4 + i;
            GLOAD_LDS16(&vt[(size_t)(h * 128 + c * 8 + r8) * kNTOK + kbase + ((j8 ^ r8) * 8)],
                        &Vs[c * 512]);
        }
        __syncthreads();

        // S = Q K^T : 16 q x 64 keys per wave
        f32x4 s[4];
        #pragma unroll
        for (int c = 0; c < 4; c++) s[c] = zero4();
        __builtin_amdgcn_s_setprio(1);
        #pragma unroll
        for (int kb = 0; kb < 4; kb++) {
            #pragma unroll
            for (int c = 0; c < 4; c++) {
                bf16x8 bfr = *(const bf16x8*)&Ks[(c * 16 + l16) * 128 + (((kb * 4 + quad) ^ l16) * 8)];
                s[c] = MFMA16(aq[kb], bfr, s[c]);
            }
        }
        __builtin_amdgcn_s_setprio(0);

        // online softmax (max via shfl; sum via ones-frag MFMA)
        float alpha[4];
        #pragma unroll
        for (int r = 0; r < 4; r++) {
            float sv[4];
            #pragma unroll
            for (int c = 0; c < 4; c++) sv[c] = s[c][r] * scale;
            float mx = fmaxf(fmaxf(sv[0], sv[1]), fmaxf(sv[2], sv[3]));
            #pragma unroll
            for (int off = 1; off < 16; off <<= 1) mx = fmaxf(mx, __shfl_xor(mx, off));
            const float mn = fmaxf(m_run[r], mx);
            alpha[r] = __expf(m_run[r] - mn);
            m_run[r] = mn;
            const int q7 = quad * 4 + r;
            #pragma unroll
            for (int c = 0; c < 4; c++) {
                const int col = (c * 16 + l16) ^ ((q7 & 7) * 8);
                Ps[wave][q7][col] = (bf16)__expf(sv[c] - mn);
            }
        }
        #pragma unroll
        for (int j2 = 0; j2 < 9; j2++)
            #pragma unroll
            for (int r = 0; r < 4; r++) o[j2][r] *= alpha[r];
        __builtin_amdgcn_s_setprio(1);
        #pragma unroll
        for (int ks = 0; ks < 2; ks++) {
            bf16x8 pa = *(const bf16x8*)&Ps[wave][l16][((ks * 4 + quad) ^ (l16 & 7)) * 8];
            #pragma unroll
            for (int j2 = 0; j2 < 8; j2++) {
                bf16x8 bv2 = *(const bf16x8*)&Vs[(j2 * 16 + l16) * 64 + (((ks * 4 + quad) ^ (l16 & 7)) * 8)];
                o[j2] = MFMA16(pa, bv2, o[j2]);
            }
            o[8] = MFMA16(pa, ones, o[8]);
        }
        __builtin_amdgcn_s_setprio(0);
    }

    #pragma unroll
    for (int r = 0; r < 4; r++) {
        const int srow = qb * 64 + wave * 16 + quad * 4 + r;
        const size_t pr = ((size_t)(z * 8 + h)) * 256 + srow;
        #pragma unroll
        for (int j2 = 0; j2 < 8; j2++)
            Opart[pr * 128 + j2 * 16 + l16] = o[j2][r];
        if (l16 == 0) { ml[pr * 2] = m_run[r]; ml[pr * 2 + 1] = o[8][r]; }
    }
}

// ---------------------------------------------------------------------------
// Combine 4 splits: O = sum O_sp*exp(m_sp-m*) / sum l_sp*exp(m_sp-m*)
// ---------------------------------------------------------------------------
__global__ __launch_bounds__(256) void combine_kernel(
    const float* __restrict__ Opart, const float* __restrict__ ml,
    float* __restrict__ out)
{
    const int tid = threadIdx.x;
    const int rid = blockIdx.x * 2 + (tid >> 7);
    const int d   = tid & 127;
    const int t = rid >> 11, h = (rid >> 8) & 7, srow = rid & 255;

    float mv[4], lv[4];
    #pragma unroll
    for (int sp = 0; sp < 4; sp++) {
        const size_t pr = ((size_t)((t * 4 + sp) * 8 + h)) * 256 + srow;
        float2 p = *(const float2*)&ml[pr * 2];
        mv[sp] = p.x; lv[sp] = p.y;
    }
    const float ms = fmaxf(fmaxf(mv[0], mv[1]), fmaxf(mv[2], mv[3]));
    float lsum = 0.f, acc = 0.f;
    #pragma unroll
    for (int sp = 0; sp < 4; sp++) {
        const size_t pr = ((size_t)((t * 4 + sp) * 8 + h)) * 256 + srow;
        const float w = __expf(mv[sp] - ms);
        lsum += lv[sp] * w;
        acc  += Opart[pr * 128 + d] * w;
    }
    out[((size_t)(t * 256 + srow)) * kDM + h * 128 + d] = acc / lsum;
}

// ---------------------------------------------------------------------------
extern "C" void kernel_launch(void* const* d_in, const int* in_sizes, int n_in,
                              void* d_out, int out_size, void* d_ws, size_t ws_size,
                              hipStream_t stream)
{
    const float* q  = (const float*)d_in[0];
    const float* k  = (const float*)d_in[1];
    const float* v  = (const float*)d_in[2];
    const float* Wq = (const float*)d_in[3];
    const float* bq = (const float*)d_in[4];
    const float* Wk = (const float*)d_in[5];
    const float* bk = (const float*)d_in[6];
    const float* Wv = (const float*)d_in[7];
    const float* bv = (const float*)d_in[8];
    float* out = (float*)d_out;

    // ws: qh 4MB | kh 64MB | vt 64MB | Wt x3 6MB | Opart 33.5MB | ml 0.5MB |
    //     Xq 4MB | Xk 64MB | Xv 64MB   (total ~304MB)
    bf16* qh  = (bf16*)d_ws;
    bf16* kh  = qh + (size_t)2048 * 1024;
    bf16* vt  = kh + (size_t)32768 * 1024;
    bf16* Wqt = vt + (size_t)32768 * 1024;
    bf16* Wkt = Wqt + (size_t)1024 * 1024;
    bf16* Wvt = Wkt + (size_t)1024 * 1024;
    float* Opart = (float*)(Wvt + (size_t)1024 * 1024);
    float* ml    = Opart + (size_t)32 * 8 * 256 * 128;
    bf16* Xq     = (bf16*)(ml + (size_t)32 * 8 * 256 * 2);
    bf16* Xk     = Xq + (size_t)2048 * 1024;
    bf16* Xv     = Xk + (size_t)32768 * 1024;

    transpose_all<<<dim3(16, 16, 3), 256, 0, stream>>>(Wq, Wk, Wv, Wqt, Wkt, Wvt);
    cvt_all<<<4096, 256, 0, stream>>>(q, k, v, Xq);
    gemm_all<<<4224, 256, 0, stream>>>(Xq, Xk, Xv, Wqt, Wkt, Wvt,
                                       bq, bk, bv, qh, kh, vt);
    attn_kernel<<<1024, 256, 0, stream>>>(qh, kh, vt, Opart, ml);
    combine_kernel<<<8192, 256, 0, stream>>>(Opart, ml, out);
}